// Round 13
// baseline (144.227 us; speedup 1.0000x reference)
//
#include <hip/hip_runtime.h>
#include <hip/hip_bf16.h>

#define DEVFN __device__ __forceinline__

typedef __attribute__((ext_vector_type(8))) __bf16 bf16x8;
typedef __attribute__((ext_vector_type(4))) float f32x4;
typedef __attribute__((ext_vector_type(16))) float f32x16;

constexpr int E  = 512;   // embed
constexpr int S  = 4096;  // seq len
constexpr int HD = 64;    // head dim
constexpr int RT = 8192;  // B * S rows

DEVFN unsigned int cvt_pk_bf16(float lo, float hi) {
  unsigned int r;
  asm("v_cvt_pk_bf16_f32 %0, %1, %2" : "=v"(r) : "v"(lo), "v"(hi));
  return r;
}
DEVFN void plswap(unsigned int& a, unsigned int& b) {
  asm("v_permlane32_swap_b32 %0, %1" : "+v"(a), "+v"(b));
}
DEVFN float ex2(float x) { return __builtin_amdgcn_exp2f(x); }

DEVFN unsigned short f2bf(float f) {
  union { float f; unsigned int u; } v; v.f = f;
  unsigned int u = v.u;
  return (unsigned short)((u + 0x7fffu + ((u >> 16) & 1u)) >> 16);
}

DEVFN f32x4 mfma16(bf16x8 a, bf16x8 b, f32x4 c) {
  return __builtin_amdgcn_mfma_f32_16x16x32_bf16(a, b, c, 0, 0, 0);
}
DEVFN f32x16 mfma32(bf16x8 a, bf16x8 b, f32x16 c) {
  return __builtin_amdgcn_mfma_f32_32x32x16_bf16(a, b, c, 0, 0, 0);
}

DEVFN uint4 pk8(const float4& a, const float4& b) {
  uint4 r;
  r.x = cvt_pk_bf16(a.x, a.y); r.y = cvt_pk_bf16(a.z, a.w);
  r.z = cvt_pk_bf16(b.x, b.y); r.w = cvt_pk_bf16(b.z, b.w);
  return r;
}
DEVFN bf16x8 asbf(uint4 u) { union { uint4 a; bf16x8 b; } c; c.a = u; return c.b; }

// ---------------------------------------------------------------------------
// GEMM (NT): out[r,n] = (sum_k X[r,k]*W[n,k] + bias[n]) * scale
// Tile 128x128, BK=64, 512 threads = 8 waves (2x4 of 64x32-out waves).
// XCD-chunked block swizzle (T1, bijective bit-permutation).
// OMODE: 0 = bf16 row-major, 1 = f32 row-major, 2 = bf16 transposed per batch
// ---------------------------------------------------------------------------
template<typename TIN, int OMODE>
DEVFN void gemm_body(const TIN* __restrict__ X, const float* __restrict__ W,
                     const float* __restrict__ bias, void* __restrict__ outp,
                     float scale, unsigned short (*Al)[72], unsigned short (*Bl)[72]) {
  const int bid0 = blockIdx.x;
  const int bid = ((bid0 & 7) << 5) | (bid0 >> 3);   // bijective, 256 blocks
  const int bm = bid >> 2, bn = bid & 3;   // 64 x 4 blocks
  const int tid = threadIdx.x;
  const int w = tid >> 6, lane = tid & 63;
  const int g = lane >> 4, ln = lane & 15;
  const int wm = w >> 2, wn = w & 3;       // 2 x 4 waves
  const int r0 = bm * 128, n0 = bn * 128;
  const int srw = tid >> 2, sc0 = (tid & 3) * 16;  // staging: 4 thr/row, 16 elems

  f32x4 acc[4][2] = {};

  float4 af[4];   // fp32 A prefetch (16 floats)
  uint4  au[2];   // bf16 A prefetch (16 elems)
  float4 bp[4];   // fp32 B prefetch

  auto loadA = [&](int k0) {
    if constexpr (sizeof(TIN) == 4) {
      const float* src = (const float*)X + (size_t)(r0 + srw) * E + k0 + sc0;
      #pragma unroll
      for (int i = 0; i < 4; ++i) af[i] = *(const float4*)(src + i * 4);
    } else {
      const unsigned short* src = (const unsigned short*)X + (size_t)(r0 + srw) * E + k0 + sc0;
      #pragma unroll
      for (int i = 0; i < 2; ++i) au[i] = *(const uint4*)(src + i * 8);
    }
  };
  auto loadB = [&](int k0) {
    const float* src = W + (size_t)(n0 + srw) * E + k0 + sc0;
    #pragma unroll
    for (int i = 0; i < 4; ++i) bp[i] = *(const float4*)(src + i * 4);
  };

  loadA(0); loadB(0);

  for (int k0 = 0; k0 < E; k0 += 64) {
    if constexpr (sizeof(TIN) == 4) {
      *(uint4*)&Al[srw][sc0]     = pk8(af[0], af[1]);
      *(uint4*)&Al[srw][sc0 + 8] = pk8(af[2], af[3]);
    } else {
      *(uint4*)&Al[srw][sc0]     = au[0];
      *(uint4*)&Al[srw][sc0 + 8] = au[1];
    }
    *(uint4*)&Bl[srw][sc0]     = pk8(bp[0], bp[1]);
    *(uint4*)&Bl[srw][sc0 + 8] = pk8(bp[2], bp[3]);
    __syncthreads();
    if (k0 + 64 < E) { loadA(k0 + 64); loadB(k0 + 64); }

    __builtin_amdgcn_s_setprio(1);
    #pragma unroll
    for (int kk = 0; kk < 2; ++kk) {
      bf16x8 afr[4], bfr[2];
      #pragma unroll
      for (int i = 0; i < 4; ++i)
        afr[i] = *(const bf16x8*)&Al[wm*64 + i*16 + ln][kk*32 + 8*g];
      #pragma unroll
      for (int j = 0; j < 2; ++j)
        bfr[j] = *(const bf16x8*)&Bl[wn*32 + j*16 + ln][kk*32 + 8*g];
      #pragma unroll
      for (int i = 0; i < 4; ++i)
        #pragma unroll
        for (int j = 0; j < 2; ++j)
          acc[i][j] = mfma16(afr[i], bfr[j], acc[i][j]);
    }
    __builtin_amdgcn_s_setprio(0);
    __syncthreads();
  }

  // epilogue: C/D layout col=lane&15, row=4*(lane>>4)+reg
  #pragma unroll
  for (int j = 0; j < 2; ++j) {
    const int gcol = n0 + wn*32 + j*16 + ln;
    const float bv = bias[gcol];
    #pragma unroll
    for (int i = 0; i < 4; ++i) {
      const int gr = r0 + wm*64 + i*16 + 4*g;
      #pragma unroll
      for (int r = 0; r < 4; ++r) {
        const float v = (acc[i][j][r] + bv) * scale;
        if constexpr (OMODE == 1)
          ((float*)outp)[(size_t)(gr + r) * E + gcol] = v;
        else if constexpr (OMODE == 0)
          ((unsigned short*)outp)[(size_t)(gr + r) * E + gcol] = f2bf(v);
        else
          ((unsigned short*)outp)[((size_t)((gr + r) >> 12) * E + gcol) * S + ((gr + r) & (S - 1))] = f2bf(v);
      }
    }
  }
}

__global__ __launch_bounds__(512) void gemm_qkv(const float* __restrict__ q,
    const float* __restrict__ k, const float* __restrict__ v,
    const float* __restrict__ Wq, const float* __restrict__ bq,
    const float* __restrict__ Wk, const float* __restrict__ bk,
    const float* __restrict__ Wv, const float* __restrict__ bv,
    unsigned short* qh, unsigned short* kh, unsigned short* vhT, float qscale) {
  __shared__ unsigned short Al[128][72];
  __shared__ unsigned short Bl[128][72];
  const int y = blockIdx.y;
  if (y == 0)      gemm_body<float, 0>(q, Wq, bq, qh, qscale, Al, Bl);
  else if (y == 1) gemm_body<float, 0>(k, Wk, bk, kh, 1.0f, Al, Bl);
  else             gemm_body<float, 2>(v, Wv, bv, vhT, 1.0f, Al, Bl);
}

__global__ __launch_bounds__(512) void gemm_o(const unsigned short* __restrict__ cc,
    const float* __restrict__ Wo, const float* __restrict__ bo, float* out) {
  __shared__ unsigned short Al[128][72];
  __shared__ unsigned short Bl[128][72];
  gemm_body<unsigned short, 1>(cc, Wo, bo, out, 1.0f, Al, Bl);
}

// ---------------------------------------------------------------------------
// Flash attention, 32x32 MFMA, in-block KV-split (R7/R9/R12-verified).
// R13 latency diet (zero register growth):
//  (1) rs computed as 4 independent 8-deep partial-sum chains (FP order
//      fixed by source, so write the tree explicitly) — was a strict
//      32-deep dependent v_add chain (~128 cy un-hideable latency).
//  (2) l kept per-lane (ll_par) across all iterations; single cross-half
//      shfl AFTER the loop. Rare-branch rescale (fr wave-uniform) exact.
//  (3) tm cross-half shfl moved INSIDE the rare branch: __all() already
//      checks all 64 lanes, so detection is exact with the lane-local max;
//      the pair-max is only needed to make delta q-consistent when firing.
//  => common path has ZERO ds_bpermute (was 2) per iteration.
// ---------------------------------------------------------------------------
__global__ __launch_bounds__(512) void attn_fwd(const unsigned short* __restrict__ qh,
                                                const unsigned short* __restrict__ kh,
                                                const unsigned short* __restrict__ vhT,
                                                unsigned short* __restrict__ cc) {
  __shared__ unsigned short SM[4][64][72];   // [2*half+0]=K [t][d], [2*half+1]=V [d][t]

  const int bid = blockIdx.x;
  const int swz = (bid & 7) * 64 + (bid >> 3);   // XCD-bijective: 2 heads/XCD-L2
  const int bh = swz >> 5, qt = swz & 31;
  const int b = bh >> 3, h = bh & 7;

  const int tid = threadIdx.x;
  const int wv = tid >> 6, lane = tid & 63;
  const int half = wv >> 2, w4 = wv & 3;
  const int l31 = lane & 31, hi = lane >> 5;

  unsigned short (*K_lds)[72] = SM[2*half];
  unsigned short (*V_lds)[72] = SM[2*half + 1];

  const unsigned short* qb = qh + (size_t)b * S * E + h * HD;
  const unsigned short* kb = kh + (size_t)b * S * E + h * HD;
  const unsigned short* vb = vhT + ((size_t)b * E + h * HD) * S;
  const int q0 = qt * 128 + w4 * 32;
  const int tbase = half * (S / 2);

  // Q as B-operand: q = q0+l31, d = kf*16 + 8*hi + j
  bf16x8 qf[4];
  #pragma unroll
  for (int kf = 0; kf < 4; ++kf)
    qf[kf] = *(const bf16x8*)(qb + (size_t)(q0 + l31) * E + kf*16 + 8*hi);

  f32x16 o0 = {}, o1 = {};
  float ml = 0.f, ll_par = 0.f;   // ml starts 0 (C-init = -ml); l per-lane

  const int t256 = tid & 255;
  const int srow = t256 >> 2, sc0 = (t256 & 3) * 16;
  const unsigned short* kS = kb + (size_t)(tbase + srow) * E + sc0;  // + it*64*E
  const unsigned short* vS = vb + (size_t)srow * S + tbase + sc0;    // + it*64

  uint4 kr0 = *(const uint4*)kS, kr1 = *(const uint4*)(kS + 8);
  uint4 vr0 = *(const uint4*)vS, vr1 = *(const uint4*)(vS + 8);

  constexpr int NIT = S / 2 / 64;   // 32 iterations per half
  for (int it = 0; it < NIT; ++it) {
    *(uint4*)&K_lds[srow][sc0]     = kr0;
    *(uint4*)&K_lds[srow][sc0 + 8] = kr1;
    *(uint4*)&V_lds[srow][sc0]     = vr0;
    *(uint4*)&V_lds[srow][sc0 + 8] = vr1;
    __syncthreads();

    if (it + 1 < NIT) {  // register prefetch of next tile (T14)
      const unsigned short* kp = kS + (size_t)(it + 1) * 64 * E;
      const unsigned short* vp = vS + (it + 1) * 64;
      kr0 = *(const uint4*)kp; kr1 = *(const uint4*)(kp + 8);
      vr0 = *(const uint4*)vp; vr1 = *(const uint4*)(vp + 8);
    }

    // ---- QK^T with C-init = -ml (scores arrive pre-shifted) ----
    const float negml = 0.f - ml;   // transient, dies before MFMA chain
    f32x16 s0, s1;
    #pragma unroll
    for (int r = 0; r < 16; ++r) { s0[r] = negml; s1[r] = negml; }
    __builtin_amdgcn_s_setprio(1);
    #pragma unroll
    for (int kf = 0; kf < 4; ++kf) {
      bf16x8 ka = *(const bf16x8*)&K_lds[l31]     [kf*16 + 8*hi];
      bf16x8 kc = *(const bf16x8*)&K_lds[32 + l31][kf*16 + 8*hi];
      s0 = mfma32(ka, qf[kf], s0);
      s1 = mfma32(kc, qf[kf], s1);
    }
    __builtin_amdgcn_s_setprio(0);

    // ---- shifted lane-local max (fmax triples -> v_max3) ----
    float m0 = fmaxf(fmaxf(s0[0],  s0[1]),  s0[2]);
    float m1 = fmaxf(fmaxf(s0[3],  s0[4]),  s0[5]);
    float m2 = fmaxf(fmaxf(s0[6],  s0[7]),  s0[8]);
    float m3 = fmaxf(fmaxf(s0[9],  s0[10]), s0[11]);
    float m4 = fmaxf(fmaxf(s0[12], s0[13]), s0[14]);
    float m5 = fmaxf(fmaxf(s0[15], s1[0]),  s1[1]);
    float m6 = fmaxf(fmaxf(s1[2],  s1[3]),  s1[4]);
    float m7 = fmaxf(fmaxf(s1[5],  s1[6]),  s1[7]);
    float m8 = fmaxf(fmaxf(s1[8],  s1[9]),  s1[10]);
    float m9 = fmaxf(fmaxf(s1[11], s1[12]), s1[13]);
    float ma = fmaxf(s1[14], s1[15]);
    float tb0 = fmaxf(fmaxf(m0, m1), m2);
    float tb1 = fmaxf(fmaxf(m3, m4), m5);
    float tb2 = fmaxf(fmaxf(m6, m7), m8);
    float tm = fmaxf(fmaxf(tb0, tb1), fmaxf(tb2, fmaxf(m9, ma)));
    // NOTE: no cross-half shuffle here — __all checks all 64 lanes.

    if (!__all(tm <= 8.f)) {   // rare exact-rescale path
      tm = fmaxf(tm, __shfl_xor(tm, 32));   // pair-max so delta is q-consistent
      const float delta = fmaxf(tm, 0.f);
      const float fr = ex2(-delta);
      ml += delta; ll_par *= fr;
      #pragma unroll
      for (int r = 0; r < 16; ++r) {
        o0[r] *= fr; o1[r] *= fr;
        s0[r] -= delta; s1[r] -= delta;
      }
    }

    // ---- P = exp2(pre-shifted score); 4 independent partial-sum chains ----
    float rsa = 0.f, rsb = 0.f, rsc = 0.f, rsd = 0.f;
    #pragma unroll
    for (int r = 0; r < 8; ++r)  { s0[r] = ex2(s0[r]); rsa += s0[r]; }
    #pragma unroll
    for (int r = 8; r < 16; ++r) { s0[r] = ex2(s0[r]); rsb += s0[r]; }
    #pragma unroll
    for (int r = 0; r < 8; ++r)  { s1[r] = ex2(s1[r]); rsc += s1[r]; }
    #pragma unroll
    for (int r = 8; r < 16; ++r) { s1[r] = ex2(s1[r]); rsd += s1[r]; }
    ll_par += (rsa + rsb) + (rsc + rsd);

    // ---- P -> B-frags in-register: cvt_pk + permlane32_swap (T12) ----
    unsigned int a0 = cvt_pk_bf16(s0[0],  s0[1]),  a1 = cvt_pk_bf16(s0[2],  s0[3]);
    unsigned int a2 = cvt_pk_bf16(s0[4],  s0[5]),  a3 = cvt_pk_bf16(s0[6],  s0[7]);
    unsigned int a4 = cvt_pk_bf16(s0[8],  s0[9]),  a5 = cvt_pk_bf16(s0[10], s0[11]);
    unsigned int a6 = cvt_pk_bf16(s0[12], s0[13]), a7 = cvt_pk_bf16(s0[14], s0[15]);
    plswap(a0, a2); plswap(a1, a3); plswap(a4, a6); plswap(a5, a7);
    unsigned int c0 = cvt_pk_bf16(s1[0],  s1[1]),  c1 = cvt_pk_bf16(s1[2],  s1[3]);
    unsigned int c2 = cvt_pk_bf16(s1[4],  s1[5]),  c3 = cvt_pk_bf16(s1[6],  s1[7]);
    unsigned int c4 = cvt_pk_bf16(s1[8],  s1[9]),  c5 = cvt_pk_bf16(s1[10], s1[11]);
    unsigned int c6 = cvt_pk_bf16(s1[12], s1[13]), c7 = cvt_pk_bf16(s1[14], s1[15]);
    plswap(c0, c2); plswap(c1, c3); plswap(c4, c6); plswap(c5, c7);
    uint4 pa[4];
    pa[0] = uint4{a0, a1, a2, a3};  // t  0..15
    pa[1] = uint4{a4, a5, a6, a7};  // t 16..31
    pa[2] = uint4{c0, c1, c2, c3};  // t 32..47
    pa[3] = uint4{c4, c5, c6, c7};  // t 48..63

    // ---- O += V^T x P : mfma32(V_frag{rows d}, P_frag{rows q}) ----
    __builtin_amdgcn_s_setprio(1);
    #pragma unroll
    for (int tf = 0; tf < 4; ++tf) {
      bf16x8 va = *(const bf16x8*)&V_lds[l31]     [tf*16 + 8*hi];
      bf16x8 vc = *(const bf16x8*)&V_lds[32 + l31][tf*16 + 8*hi];
      bf16x8 pf = asbf(pa[tf]);
      o0 = mfma32(va, pf, o0);
      o1 = mfma32(vc, pf, o1);
    }
    __builtin_amdgcn_s_setprio(0);
    __syncthreads();
  }

  // ---- combine per-lane l across the lane^32 pair (deferred from loop) ----
  float ll = ll_par + __shfl_xor(ll_par, 32);

  // ---- flash-combine across the two KV-halves via LDS ----
  // per (w4, lane): 34 floats {o0[16], o1[16], ml, ll}. stride 34 -> 2-way.
  float* cb = (float*)SM;
  float* p = cb + (size_t)(w4 * 64 + lane) * 34;
  if (half) {
    #pragma unroll
    for (int r = 0; r < 16; ++r) { p[r] = o0[r]; p[16 + r] = o1[r]; }
    p[32] = ml; p[33] = ll;
  }
  __syncthreads();
  if (!half) {
    const float m2 = p[32], l2 = p[33];
    const float m = fmaxf(ml, m2);
    const float f1 = ex2(ml - m), f2 = ex2(m2 - m);
    ll = ll * f1 + l2 * f2;
    #pragma unroll
    for (int r = 0; r < 16; ++r) {
      o0[r] = o0[r] * f1 + p[r] * f2;
      o1[r] = o1[r] * f1 + p[16 + r] * f2;
    }

    // ---- epilogue: d = (r&3)+8*(r>>2)+4*hi (+32 for o1), col q = l31 ----
    const float inv = 1.0f / ll;
    const size_t rowb = (size_t)(b * S + q0 + l31) * E + h * HD;
    #pragma unroll
    for (int qd = 0; qd < 4; ++qd) {
      uint2 w0, w1;
      w0.x = cvt_pk_bf16(o0[4*qd]     * inv, o0[4*qd + 1] * inv);
      w0.y = cvt_pk_bf16(o0[4*qd + 2] * inv, o0[4*qd + 3] * inv);
      *(uint2*)&cc[rowb + 8*qd + 4*hi] = w0;
      w1.x = cvt_pk_bf16(o1[4*qd]     * inv, o1[4*qd + 1] * inv);
      w1.y = cvt_pk_bf16(o1[4*qd + 2] * inv, o1[4*qd + 3] * inv);
      *(uint2*)&cc[rowb + 32 + 8*qd + 4*hi] = w1;
    }
  }
}

// ---------------------------------------------------------------------------
extern "C" void kernel_launch(void* const* d_in, const int* in_sizes, int n_in,
                              void* d_out, int out_size, void* d_ws, size_t ws_size,
                              hipStream_t stream) {
  const float* q  = (const float*)d_in[0];
  const float* k  = (const float*)d_in[1];
  const float* v  = (const float*)d_in[2];
  const float* Wq = (const float*)d_in[3];
  const float* bq = (const float*)d_in[4];
  const float* Wk = (const float*)d_in[5];
  const float* bk = (const float*)d_in[6];
  const float* Wv = (const float*)d_in[7];
  const float* bv = (const float*)d_in[8];
  const float* Wo = (const float*)d_in[9];
  const float* bo = (const float*)d_in[10];
  float* out = (float*)d_out;

  unsigned short* qh  = (unsigned short*)d_ws;
  unsigned short* kh  = qh + (size_t)RT * E;
  unsigned short* vhT = kh + (size_t)RT * E;
  unsigned short* cc  = vhT + (size_t)RT * E;

  // 1/sqrt(512) * log2(e): softmax runs in base-2 domain
  const float qscale = 1.4426950408889634f / 22.62741699796952f;

  gemm_qkv<<<dim3(256, 3), dim3(512), 0, stream>>>(q, k, v, Wq, bq, Wk, bk, Wv, bv,
                                                   qh, kh, vhT, qscale);
  attn_fwd<<<dim3(512), dim3(512), 0, stream>>>(qh, kh, vhT, cc);
  gemm_o<<<dim3(256), dim3(512), 0, stream>>>(cc, Wo, bo, out);
}

// Round 14
// 138.425 us; speedup vs baseline: 1.0419x; 1.0419x over previous
//
#include <hip/hip_runtime.h>
#include <hip/hip_bf16.h>

#define DEVFN __device__ __forceinline__

typedef __attribute__((ext_vector_type(8))) __bf16 bf16x8;
typedef __attribute__((ext_vector_type(4))) float f32x4;
typedef __attribute__((ext_vector_type(16))) float f32x16;

constexpr int E  = 512;   // embed
constexpr int S  = 4096;  // seq len
constexpr int HD = 64;    // head dim
constexpr int RT = 8192;  // B * S rows

DEVFN unsigned int cvt_pk_bf16(float lo, float hi) {
  unsigned int r;
  asm("v_cvt_pk_bf16_f32 %0, %1, %2" : "=v"(r) : "v"(lo), "v"(hi));
  return r;
}
DEVFN void plswap(unsigned int& a, unsigned int& b) {
  asm("v_permlane32_swap_b32 %0, %1" : "+v"(a), "+v"(b));
}
DEVFN float ex2(float x) { return __builtin_amdgcn_exp2f(x); }

DEVFN unsigned short f2bf(float f) {
  union { float f; unsigned int u; } v; v.f = f;
  unsigned int u = v.u;
  return (unsigned short)((u + 0x7fffu + ((u >> 16) & 1u)) >> 16);
}

DEVFN f32x4 mfma16(bf16x8 a, bf16x8 b, f32x4 c) {
  return __builtin_amdgcn_mfma_f32_16x16x32_bf16(a, b, c, 0, 0, 0);
}
DEVFN f32x16 mfma32(bf16x8 a, bf16x8 b, f32x16 c) {
  return __builtin_amdgcn_mfma_f32_32x32x16_bf16(a, b, c, 0, 0, 0);
}

DEVFN uint4 pk8(const float4& a, const float4& b) {
  uint4 r;
  r.x = cvt_pk_bf16(a.x, a.y); r.y = cvt_pk_bf16(a.z, a.w);
  r.z = cvt_pk_bf16(b.x, b.y); r.w = cvt_pk_bf16(b.z, b.w);
  return r;
}
DEVFN bf16x8 asbf(uint4 u) { union { uint4 a; bf16x8 b; } c; c.a = u; return c.b; }

// ---------------------------------------------------------------------------
// GEMM (NT): out[r,n] = (sum_k X[r,k]*W[n,k] + bias[n]) * scale
// Tile 128x128, BK=64, 512 threads = 8 waves (2x4 of 64x32-out waves).
// XCD-chunked block swizzle (T1, bijective bit-permutation).
// OMODE: 0 = bf16 row-major, 1 = f32 row-major, 2 = bf16 transposed per batch
// ---------------------------------------------------------------------------
template<typename TIN, int OMODE>
DEVFN void gemm_body(const TIN* __restrict__ X, const float* __restrict__ W,
                     const float* __restrict__ bias, void* __restrict__ outp,
                     float scale, unsigned short (*Al)[72], unsigned short (*Bl)[72]) {
  const int bid0 = blockIdx.x;
  const int bid = ((bid0 & 7) << 5) | (bid0 >> 3);   // bijective, 256 blocks
  const int bm = bid >> 2, bn = bid & 3;   // 64 x 4 blocks
  const int tid = threadIdx.x;
  const int w = tid >> 6, lane = tid & 63;
  const int g = lane >> 4, ln = lane & 15;
  const int wm = w >> 2, wn = w & 3;       // 2 x 4 waves
  const int r0 = bm * 128, n0 = bn * 128;
  const int srw = tid >> 2, sc0 = (tid & 3) * 16;  // staging: 4 thr/row, 16 elems

  f32x4 acc[4][2] = {};

  float4 af[4];   // fp32 A prefetch (16 floats)
  uint4  au[2];   // bf16 A prefetch (16 elems)
  float4 bp[4];   // fp32 B prefetch

  auto loadA = [&](int k0) {
    if constexpr (sizeof(TIN) == 4) {
      const float* src = (const float*)X + (size_t)(r0 + srw) * E + k0 + sc0;
      #pragma unroll
      for (int i = 0; i < 4; ++i) af[i] = *(const float4*)(src + i * 4);
    } else {
      const unsigned short* src = (const unsigned short*)X + (size_t)(r0 + srw) * E + k0 + sc0;
      #pragma unroll
      for (int i = 0; i < 2; ++i) au[i] = *(const uint4*)(src + i * 8);
    }
  };
  auto loadB = [&](int k0) {
    const float* src = W + (size_t)(n0 + srw) * E + k0 + sc0;
    #pragma unroll
    for (int i = 0; i < 4; ++i) bp[i] = *(const float4*)(src + i * 4);
  };

  loadA(0); loadB(0);

  for (int k0 = 0; k0 < E; k0 += 64) {
    if constexpr (sizeof(TIN) == 4) {
      *(uint4*)&Al[srw][sc0]     = pk8(af[0], af[1]);
      *(uint4*)&Al[srw][sc0 + 8] = pk8(af[2], af[3]);
    } else {
      *(uint4*)&Al[srw][sc0]     = au[0];
      *(uint4*)&Al[srw][sc0 + 8] = au[1];
    }
    *(uint4*)&Bl[srw][sc0]     = pk8(bp[0], bp[1]);
    *(uint4*)&Bl[srw][sc0 + 8] = pk8(bp[2], bp[3]);
    __syncthreads();
    if (k0 + 64 < E) { loadA(k0 + 64); loadB(k0 + 64); }

    __builtin_amdgcn_s_setprio(1);
    #pragma unroll
    for (int kk = 0; kk < 2; ++kk) {
      bf16x8 afr[4], bfr[2];
      #pragma unroll
      for (int i = 0; i < 4; ++i)
        afr[i] = *(const bf16x8*)&Al[wm*64 + i*16 + ln][kk*32 + 8*g];
      #pragma unroll
      for (int j = 0; j < 2; ++j)
        bfr[j] = *(const bf16x8*)&Bl[wn*32 + j*16 + ln][kk*32 + 8*g];
      #pragma unroll
      for (int i = 0; i < 4; ++i)
        #pragma unroll
        for (int j = 0; j < 2; ++j)
          acc[i][j] = mfma16(afr[i], bfr[j], acc[i][j]);
    }
    __builtin_amdgcn_s_setprio(0);
    __syncthreads();
  }

  // epilogue: C/D layout col=lane&15, row=4*(lane>>4)+reg
  #pragma unroll
  for (int j = 0; j < 2; ++j) {
    const int gcol = n0 + wn*32 + j*16 + ln;
    const float bv = bias[gcol];
    #pragma unroll
    for (int i = 0; i < 4; ++i) {
      const int gr = r0 + wm*64 + i*16 + 4*g;
      #pragma unroll
      for (int r = 0; r < 4; ++r) {
        const float v = (acc[i][j][r] + bv) * scale;
        if constexpr (OMODE == 1)
          ((float*)outp)[(size_t)(gr + r) * E + gcol] = v;
        else if constexpr (OMODE == 0)
          ((unsigned short*)outp)[(size_t)(gr + r) * E + gcol] = f2bf(v);
        else
          ((unsigned short*)outp)[((size_t)((gr + r) >> 12) * E + gcol) * S + ((gr + r) & (S - 1))] = f2bf(v);
      }
    }
  }
}

__global__ __launch_bounds__(512) void gemm_qkv(const float* __restrict__ q,
    const float* __restrict__ k, const float* __restrict__ v,
    const float* __restrict__ Wq, const float* __restrict__ bq,
    const float* __restrict__ Wk, const float* __restrict__ bk,
    const float* __restrict__ Wv, const float* __restrict__ bv,
    unsigned short* qh, unsigned short* kh, unsigned short* vhT, float qscale) {
  __shared__ unsigned short Al[128][72];
  __shared__ unsigned short Bl[128][72];
  const int y = blockIdx.y;
  if (y == 0)      gemm_body<float, 0>(q, Wq, bq, qh, qscale, Al, Bl);
  else if (y == 1) gemm_body<float, 0>(k, Wk, bk, kh, 1.0f, Al, Bl);
  else             gemm_body<float, 2>(v, Wv, bv, vhT, 1.0f, Al, Bl);
}

__global__ __launch_bounds__(512) void gemm_o(const unsigned short* __restrict__ cc,
    const float* __restrict__ Wo, const float* __restrict__ bo, float* out) {
  __shared__ unsigned short Al[128][72];
  __shared__ unsigned short Bl[128][72];
  gemm_body<unsigned short, 1>(cc, Wo, bo, out, 1.0f, Al, Bl);
}

// ---------------------------------------------------------------------------
// Flash attention, 32x32 MFMA, in-block KV-split (R7/R9/R12-verified).
// R14 = R12 + R13's verified latency edits, register-budgeted:
//  (1) tm cross-half shfl only inside the rare branch (common path: 0
//      ds_bpermute; __all checks all 64 lanes so detection stays exact).
//  (2) l per-lane (ll_par); one cross-half shfl after the loop.
//  (3) rs as TWO partial chains (one per s-vector; +1 transient reg) —
//      R13's 4-way (+3 regs) crossed the 128/wave cliff (64->68 arch,
//      occupancy 36->21.7%, dur +14us despite VALUBusy 53->39).
//  __launch_bounds__(512, 4) enforces >=4 waves/SIMD (<=128 regs/wave):
//  a 1-2 reg overrun becomes a visible cold-path spill, not a silent
//  occupancy halving (the failure mode of R10/R11/R13).
// ---------------------------------------------------------------------------
__global__ __launch_bounds__(512, 4) void attn_fwd(const unsigned short* __restrict__ qh,
                                                   const unsigned short* __restrict__ kh,
                                                   const unsigned short* __restrict__ vhT,
                                                   unsigned short* __restrict__ cc) {
  __shared__ unsigned short SM[4][64][72];   // [2*half+0]=K [t][d], [2*half+1]=V [d][t]

  const int bid = blockIdx.x;
  const int swz = (bid & 7) * 64 + (bid >> 3);   // XCD-bijective: 2 heads/XCD-L2
  const int bh = swz >> 5, qt = swz & 31;
  const int b = bh >> 3, h = bh & 7;

  const int tid = threadIdx.x;
  const int wv = tid >> 6, lane = tid & 63;
  const int half = wv >> 2, w4 = wv & 3;
  const int l31 = lane & 31, hi = lane >> 5;

  unsigned short (*K_lds)[72] = SM[2*half];
  unsigned short (*V_lds)[72] = SM[2*half + 1];

  const unsigned short* qb = qh + (size_t)b * S * E + h * HD;
  const unsigned short* kb = kh + (size_t)b * S * E + h * HD;
  const unsigned short* vb = vhT + ((size_t)b * E + h * HD) * S;
  const int q0 = qt * 128 + w4 * 32;
  const int tbase = half * (S / 2);

  // Q as B-operand: q = q0+l31, d = kf*16 + 8*hi + j
  bf16x8 qf[4];
  #pragma unroll
  for (int kf = 0; kf < 4; ++kf)
    qf[kf] = *(const bf16x8*)(qb + (size_t)(q0 + l31) * E + kf*16 + 8*hi);

  f32x16 o0 = {}, o1 = {};
  float ml = 0.f, ll_par = 0.f;   // ml starts 0 (C-init = -ml); l per-lane

  const int t256 = tid & 255;
  const int srow = t256 >> 2, sc0 = (t256 & 3) * 16;
  const unsigned short* kS = kb + (size_t)(tbase + srow) * E + sc0;  // + it*64*E
  const unsigned short* vS = vb + (size_t)srow * S + tbase + sc0;    // + it*64

  uint4 kr0 = *(const uint4*)kS, kr1 = *(const uint4*)(kS + 8);
  uint4 vr0 = *(const uint4*)vS, vr1 = *(const uint4*)(vS + 8);

  constexpr int NIT = S / 2 / 64;   // 32 iterations per half
  for (int it = 0; it < NIT; ++it) {
    *(uint4*)&K_lds[srow][sc0]     = kr0;
    *(uint4*)&K_lds[srow][sc0 + 8] = kr1;
    *(uint4*)&V_lds[srow][sc0]     = vr0;
    *(uint4*)&V_lds[srow][sc0 + 8] = vr1;
    __syncthreads();

    if (it + 1 < NIT) {  // register prefetch of next tile (T14)
      const unsigned short* kp = kS + (size_t)(it + 1) * 64 * E;
      const unsigned short* vp = vS + (it + 1) * 64;
      kr0 = *(const uint4*)kp; kr1 = *(const uint4*)(kp + 8);
      vr0 = *(const uint4*)vp; vr1 = *(const uint4*)(vp + 8);
    }

    // ---- QK^T with C-init = -ml (scores arrive pre-shifted) ----
    const float negml = 0.f - ml;   // transient, dies before MFMA chain
    f32x16 s0, s1;
    #pragma unroll
    for (int r = 0; r < 16; ++r) { s0[r] = negml; s1[r] = negml; }
    __builtin_amdgcn_s_setprio(1);
    #pragma unroll
    for (int kf = 0; kf < 4; ++kf) {
      bf16x8 ka = *(const bf16x8*)&K_lds[l31]     [kf*16 + 8*hi];
      bf16x8 kc = *(const bf16x8*)&K_lds[32 + l31][kf*16 + 8*hi];
      s0 = mfma32(ka, qf[kf], s0);
      s1 = mfma32(kc, qf[kf], s1);
    }
    __builtin_amdgcn_s_setprio(0);

    // ---- shifted lane-local max (fmax triples -> v_max3) ----
    float m0 = fmaxf(fmaxf(s0[0],  s0[1]),  s0[2]);
    float m1 = fmaxf(fmaxf(s0[3],  s0[4]),  s0[5]);
    float m2 = fmaxf(fmaxf(s0[6],  s0[7]),  s0[8]);
    float m3 = fmaxf(fmaxf(s0[9],  s0[10]), s0[11]);
    float m4 = fmaxf(fmaxf(s0[12], s0[13]), s0[14]);
    float m5 = fmaxf(fmaxf(s0[15], s1[0]),  s1[1]);
    float m6 = fmaxf(fmaxf(s1[2],  s1[3]),  s1[4]);
    float m7 = fmaxf(fmaxf(s1[5],  s1[6]),  s1[7]);
    float m8 = fmaxf(fmaxf(s1[8],  s1[9]),  s1[10]);
    float m9 = fmaxf(fmaxf(s1[11], s1[12]), s1[13]);
    float ma = fmaxf(s1[14], s1[15]);
    float tb0 = fmaxf(fmaxf(m0, m1), m2);
    float tb1 = fmaxf(fmaxf(m3, m4), m5);
    float tb2 = fmaxf(fmaxf(m6, m7), m8);
    float tm = fmaxf(fmaxf(tb0, tb1), fmaxf(tb2, fmaxf(m9, ma)));
    // no cross-half shuffle here — __all checks all 64 lanes (exact)

    if (!__all(tm <= 8.f)) {   // rare exact-rescale path (R13-verified)
      tm = fmaxf(tm, __shfl_xor(tm, 32));   // pair-max so delta is q-consistent
      const float delta = fmaxf(tm, 0.f);
      const float fr = ex2(-delta);
      ml += delta; ll_par *= fr;
      #pragma unroll
      for (int r = 0; r < 16; ++r) {
        o0[r] *= fr; o1[r] *= fr;
        s0[r] -= delta; s1[r] -= delta;
      }
    }

    // ---- P = exp2(pre-shifted score); two partial-sum chains ----
    float rs0 = 0.f, rs1 = 0.f;
    #pragma unroll
    for (int r = 0; r < 16; ++r) { s0[r] = ex2(s0[r]); rs0 += s0[r]; }
    #pragma unroll
    for (int r = 0; r < 16; ++r) { s1[r] = ex2(s1[r]); rs1 += s1[r]; }
    ll_par += rs0 + rs1;

    // ---- P -> B-frags in-register: cvt_pk + permlane32_swap (T12) ----
    unsigned int a0 = cvt_pk_bf16(s0[0],  s0[1]),  a1 = cvt_pk_bf16(s0[2],  s0[3]);
    unsigned int a2 = cvt_pk_bf16(s0[4],  s0[5]),  a3 = cvt_pk_bf16(s0[6],  s0[7]);
    unsigned int a4 = cvt_pk_bf16(s0[8],  s0[9]),  a5 = cvt_pk_bf16(s0[10], s0[11]);
    unsigned int a6 = cvt_pk_bf16(s0[12], s0[13]), a7 = cvt_pk_bf16(s0[14], s0[15]);
    plswap(a0, a2); plswap(a1, a3); plswap(a4, a6); plswap(a5, a7);
    unsigned int c0 = cvt_pk_bf16(s1[0],  s1[1]),  c1 = cvt_pk_bf16(s1[2],  s1[3]);
    unsigned int c2 = cvt_pk_bf16(s1[4],  s1[5]),  c3 = cvt_pk_bf16(s1[6],  s1[7]);
    unsigned int c4 = cvt_pk_bf16(s1[8],  s1[9]),  c5 = cvt_pk_bf16(s1[10], s1[11]);
    unsigned int c6 = cvt_pk_bf16(s1[12], s1[13]), c7 = cvt_pk_bf16(s1[14], s1[15]);
    plswap(c0, c2); plswap(c1, c3); plswap(c4, c6); plswap(c5, c7);
    uint4 pa[4];
    pa[0] = uint4{a0, a1, a2, a3};  // t  0..15
    pa[1] = uint4{a4, a5, a6, a7};  // t 16..31
    pa[2] = uint4{c0, c1, c2, c3};  // t 32..47
    pa[3] = uint4{c4, c5, c6, c7};  // t 48..63

    // ---- O += V^T x P : mfma32(V_frag{rows d}, P_frag{rows q}) ----
    __builtin_amdgcn_s_setprio(1);
    #pragma unroll
    for (int tf = 0; tf < 4; ++tf) {
      bf16x8 va = *(const bf16x8*)&V_lds[l31]     [tf*16 + 8*hi];
      bf16x8 vc = *(const bf16x8*)&V_lds[32 + l31][tf*16 + 8*hi];
      bf16x8 pf = asbf(pa[tf]);
      o0 = mfma32(va, pf, o0);
      o1 = mfma32(vc, pf, o1);
    }
    __builtin_amdgcn_s_setprio(0);
    __syncthreads();
  }

  // ---- combine per-lane l across the lane^32 pair (deferred from loop) ----
  float ll = ll_par + __shfl_xor(ll_par, 32);

  // ---- flash-combine across the two KV-halves via LDS ----
  // per (w4, lane): 34 floats {o0[16], o1[16], ml, ll}. stride 34 -> 2-way.
  float* cb = (float*)SM;
  float* p = cb + (size_t)(w4 * 64 + lane) * 34;
  if (half) {
    #pragma unroll
    for (int r = 0; r < 16; ++r) { p[r] = o0[r]; p[16 + r] = o1[r]; }
    p[32] = ml; p[33] = ll;
  }
  __syncthreads();
  if (!half) {
    const float m2 = p[32], l2 = p[33];
    const float m = fmaxf(ml, m2);
    const float f1 = ex2(ml - m), f2 = ex2(m2 - m);
    ll = ll * f1 + l2 * f2;
    #pragma unroll
    for (int r = 0; r < 16; ++r) {
      o0[r] = o0[r] * f1 + p[r] * f2;
      o1[r] = o1[r] * f1 + p[16 + r] * f2;
    }

    // ---- epilogue: d = (r&3)+8*(r>>2)+4*hi (+32 for o1), col q = l31 ----
    const float inv = 1.0f / ll;
    const size_t rowb = (size_t)(b * S + q0 + l31) * E + h * HD;
    #pragma unroll
    for (int qd = 0; qd < 4; ++qd) {
      uint2 w0, w1;
      w0.x = cvt_pk_bf16(o0[4*qd]     * inv, o0[4*qd + 1] * inv);
      w0.y = cvt_pk_bf16(o0[4*qd + 2] * inv, o0[4*qd + 3] * inv);
      *(uint2*)&cc[rowb + 8*qd + 4*hi] = w0;
      w1.x = cvt_pk_bf16(o1[4*qd]     * inv, o1[4*qd + 1] * inv);
      w1.y = cvt_pk_bf16(o1[4*qd + 2] * inv, o1[4*qd + 3] * inv);
      *(uint2*)&cc[rowb + 32 + 8*qd + 4*hi] = w1;
    }
  }
}

// ---------------------------------------------------------------------------
extern "C" void kernel_launch(void* const* d_in, const int* in_sizes, int n_in,
                              void* d_out, int out_size, void* d_ws, size_t ws_size,
                              hipStream_t stream) {
  const float* q  = (const float*)d_in[0];
  const float* k  = (const float*)d_in[1];
  const float* v  = (const float*)d_in[2];
  const float* Wq = (const float*)d_in[3];
  const float* bq = (const float*)d_in[4];
  const float* Wk = (const float*)d_in[5];
  const float* bk = (const float*)d_in[6];
  const float* Wv = (const float*)d_in[7];
  const float* bv = (const float*)d_in[8];
  const float* Wo = (const float*)d_in[9];
  const float* bo = (const float*)d_in[10];
  float* out = (float*)d_out;

  unsigned short* qh  = (unsigned short*)d_ws;
  unsigned short* kh  = qh + (size_t)RT * E;
  unsigned short* vhT = kh + (size_t)RT * E;
  unsigned short* cc  = vhT + (size_t)RT * E;

  // 1/sqrt(512) * log2(e): softmax runs in base-2 domain
  const float qscale = 1.4426950408889634f / 22.62741699796952f;

  gemm_qkv<<<dim3(256, 3), dim3(512), 0, stream>>>(q, k, v, Wq, bq, Wk, bk, Wv, bv,
                                                   qh, kh, vhT, qscale);
  attn_fwd<<<dim3(512), dim3(512), 0, stream>>>(qh, kh, vhT, cc);
  gemm_o<<<dim3(256), dim3(512), 0, stream>>>(cc, Wo, bo, out);
}

// Round 15
// 135.839 us; speedup vs baseline: 1.0617x; 1.0190x over previous
//
#include <hip/hip_runtime.h>
#include <hip/hip_bf16.h>

#define DEVFN __device__ __forceinline__

typedef __attribute__((ext_vector_type(8))) __bf16 bf16x8;
typedef __attribute__((ext_vector_type(4))) float f32x4;
typedef __attribute__((ext_vector_type(16))) float f32x16;

constexpr int E  = 512;   // embed
constexpr int S  = 4096;  // seq len
constexpr int HD = 64;    // head dim
constexpr int RT = 8192;  // B * S rows

DEVFN unsigned int cvt_pk_bf16(float lo, float hi) {
  unsigned int r;
  asm("v_cvt_pk_bf16_f32 %0, %1, %2" : "=v"(r) : "v"(lo), "v"(hi));
  return r;
}
DEVFN void plswap(unsigned int& a, unsigned int& b) {
  asm("v_permlane32_swap_b32 %0, %1" : "+v"(a), "+v"(b));
}
DEVFN float ex2(float x) { return __builtin_amdgcn_exp2f(x); }

DEVFN unsigned short f2bf(float f) {
  union { float f; unsigned int u; } v; v.f = f;
  unsigned int u = v.u;
  return (unsigned short)((u + 0x7fffu + ((u >> 16) & 1u)) >> 16);
}

DEVFN f32x4 mfma16(bf16x8 a, bf16x8 b, f32x4 c) {
  return __builtin_amdgcn_mfma_f32_16x16x32_bf16(a, b, c, 0, 0, 0);
}
DEVFN f32x16 mfma32(bf16x8 a, bf16x8 b, f32x16 c) {
  return __builtin_amdgcn_mfma_f32_32x32x16_bf16(a, b, c, 0, 0, 0);
}

DEVFN uint4 pk8(const float4& a, const float4& b) {
  uint4 r;
  r.x = cvt_pk_bf16(a.x, a.y); r.y = cvt_pk_bf16(a.z, a.w);
  r.z = cvt_pk_bf16(b.x, b.y); r.w = cvt_pk_bf16(b.z, b.w);
  return r;
}
DEVFN bf16x8 asbf(uint4 u) { union { uint4 a; bf16x8 b; } c; c.a = u; return c.b; }

// ---------------------------------------------------------------------------
// GEMM (NT): out[r,n] = (sum_k X[r,k]*W[n,k] + bias[n]) * scale
// Tile 128x128, BK=64, 512 threads = 8 waves (2x4 of 64x32-out waves).
// XCD-chunked block swizzle (T1, bijective bit-permutation).
// OMODE: 0 = bf16 row-major, 1 = f32 row-major, 2 = bf16 transposed per batch
// ---------------------------------------------------------------------------
template<typename TIN, int OMODE>
DEVFN void gemm_body(const TIN* __restrict__ X, const float* __restrict__ W,
                     const float* __restrict__ bias, void* __restrict__ outp,
                     float scale, unsigned short (*Al)[72], unsigned short (*Bl)[72]) {
  const int bid0 = blockIdx.x;
  const int bid = ((bid0 & 7) << 5) | (bid0 >> 3);   // bijective, 256 blocks
  const int bm = bid >> 2, bn = bid & 3;   // 64 x 4 blocks
  const int tid = threadIdx.x;
  const int w = tid >> 6, lane = tid & 63;
  const int g = lane >> 4, ln = lane & 15;
  const int wm = w >> 2, wn = w & 3;       // 2 x 4 waves
  const int r0 = bm * 128, n0 = bn * 128;
  const int srw = tid >> 2, sc0 = (tid & 3) * 16;  // staging: 4 thr/row, 16 elems

  f32x4 acc[4][2] = {};

  float4 af[4];   // fp32 A prefetch (16 floats)
  uint4  au[2];   // bf16 A prefetch (16 elems)
  float4 bp[4];   // fp32 B prefetch

  auto loadA = [&](int k0) {
    if constexpr (sizeof(TIN) == 4) {
      const float* src = (const float*)X + (size_t)(r0 + srw) * E + k0 + sc0;
      #pragma unroll
      for (int i = 0; i < 4; ++i) af[i] = *(const float4*)(src + i * 4);
    } else {
      const unsigned short* src = (const unsigned short*)X + (size_t)(r0 + srw) * E + k0 + sc0;
      #pragma unroll
      for (int i = 0; i < 2; ++i) au[i] = *(const uint4*)(src + i * 8);
    }
  };
  auto loadB = [&](int k0) {
    const float* src = W + (size_t)(n0 + srw) * E + k0 + sc0;
    #pragma unroll
    for (int i = 0; i < 4; ++i) bp[i] = *(const float4*)(src + i * 4);
  };

  loadA(0); loadB(0);

  for (int k0 = 0; k0 < E; k0 += 64) {
    if constexpr (sizeof(TIN) == 4) {
      *(uint4*)&Al[srw][sc0]     = pk8(af[0], af[1]);
      *(uint4*)&Al[srw][sc0 + 8] = pk8(af[2], af[3]);
    } else {
      *(uint4*)&Al[srw][sc0]     = au[0];
      *(uint4*)&Al[srw][sc0 + 8] = au[1];
    }
    *(uint4*)&Bl[srw][sc0]     = pk8(bp[0], bp[1]);
    *(uint4*)&Bl[srw][sc0 + 8] = pk8(bp[2], bp[3]);
    __syncthreads();
    if (k0 + 64 < E) { loadA(k0 + 64); loadB(k0 + 64); }

    __builtin_amdgcn_s_setprio(1);
    #pragma unroll
    for (int kk = 0; kk < 2; ++kk) {
      bf16x8 afr[4], bfr[2];
      #pragma unroll
      for (int i = 0; i < 4; ++i)
        afr[i] = *(const bf16x8*)&Al[wm*64 + i*16 + ln][kk*32 + 8*g];
      #pragma unroll
      for (int j = 0; j < 2; ++j)
        bfr[j] = *(const bf16x8*)&Bl[wn*32 + j*16 + ln][kk*32 + 8*g];
      #pragma unroll
      for (int i = 0; i < 4; ++i)
        #pragma unroll
        for (int j = 0; j < 2; ++j)
          acc[i][j] = mfma16(afr[i], bfr[j], acc[i][j]);
    }
    __builtin_amdgcn_s_setprio(0);
    __syncthreads();
  }

  // epilogue: C/D layout col=lane&15, row=4*(lane>>4)+reg
  #pragma unroll
  for (int j = 0; j < 2; ++j) {
    const int gcol = n0 + wn*32 + j*16 + ln;
    const float bv = bias[gcol];
    #pragma unroll
    for (int i = 0; i < 4; ++i) {
      const int gr = r0 + wm*64 + i*16 + 4*g;
      #pragma unroll
      for (int r = 0; r < 4; ++r) {
        const float v = (acc[i][j][r] + bv) * scale;
        if constexpr (OMODE == 1)
          ((float*)outp)[(size_t)(gr + r) * E + gcol] = v;
        else if constexpr (OMODE == 0)
          ((unsigned short*)outp)[(size_t)(gr + r) * E + gcol] = f2bf(v);
        else
          ((unsigned short*)outp)[((size_t)((gr + r) >> 12) * E + gcol) * S + ((gr + r) & (S - 1))] = f2bf(v);
      }
    }
  }
}

__global__ __launch_bounds__(512) void gemm_qkv(const float* __restrict__ q,
    const float* __restrict__ k, const float* __restrict__ v,
    const float* __restrict__ Wq, const float* __restrict__ bq,
    const float* __restrict__ Wk, const float* __restrict__ bk,
    const float* __restrict__ Wv, const float* __restrict__ bv,
    unsigned short* qh, unsigned short* kh, unsigned short* vhT, float qscale) {
  __shared__ unsigned short Al[128][72];
  __shared__ unsigned short Bl[128][72];
  const int y = blockIdx.y;
  if (y == 0)      gemm_body<float, 0>(q, Wq, bq, qh, qscale, Al, Bl);
  else if (y == 1) gemm_body<float, 0>(k, Wk, bk, kh, 1.0f, Al, Bl);
  else             gemm_body<float, 2>(v, Wv, bv, vhT, 1.0f, Al, Bl);
}

__global__ __launch_bounds__(512) void gemm_o(const unsigned short* __restrict__ cc,
    const float* __restrict__ Wo, const float* __restrict__ bo, float* out) {
  __shared__ unsigned short Al[128][72];
  __shared__ unsigned short Bl[128][72];
  gemm_body<unsigned short, 1>(cc, Wo, bo, out, 1.0f, Al, Bl);
}

// ---------------------------------------------------------------------------
// Flash attention, 32x32 MFMA, in-block KV-split (R7/R9/R12/R14-verified).
// R15: DOUBLE-BUFFERED KV staging LDS -> ONE barrier per iteration (was 2).
// Grid = 512 blocks = exactly 2 blocks/CU, so LDS 36.9->73.7 KB is free
// (2 x 73.7 = 147 < 160 KB; occupancy unchanged). Per iter: write staged
// regs into buf[it&1] -> barrier -> prefetch + compute from buf[it&1].
// Race-free with 2 buffers + 1 barrier: adjacent barrier segments touch
// different buffers (a wave is at most one segment ahead). Staging
// ds_writes now overlap the previous compute's shadow instead of sitting
// between two barriers. Softmax/pack/PV identical to R14 (PASS, VGPR 64).
// ---------------------------------------------------------------------------
__global__ __launch_bounds__(512, 4) void attn_fwd(const unsigned short* __restrict__ qh,
                                                   const unsigned short* __restrict__ kh,
                                                   const unsigned short* __restrict__ vhT,
                                                   unsigned short* __restrict__ cc) {
  // [buf][2*half+0]=K [t][d], [buf][2*half+1]=V [d][t]; 73,728 B total
  __shared__ unsigned short SM[2][4][64][72];

  const int bid = blockIdx.x;
  const int swz = (bid & 7) * 64 + (bid >> 3);   // XCD-bijective: 2 heads/XCD-L2
  const int bh = swz >> 5, qt = swz & 31;
  const int b = bh >> 3, h = bh & 7;

  const int tid = threadIdx.x;
  const int wv = tid >> 6, lane = tid & 63;
  const int half = wv >> 2, w4 = wv & 3;
  const int l31 = lane & 31, hi = lane >> 5;

  const unsigned short* qb = qh + (size_t)b * S * E + h * HD;
  const unsigned short* kb = kh + (size_t)b * S * E + h * HD;
  const unsigned short* vb = vhT + ((size_t)b * E + h * HD) * S;
  const int q0 = qt * 128 + w4 * 32;
  const int tbase = half * (S / 2);

  // Q as B-operand: q = q0+l31, d = kf*16 + 8*hi + j
  bf16x8 qf[4];
  #pragma unroll
  for (int kf = 0; kf < 4; ++kf)
    qf[kf] = *(const bf16x8*)(qb + (size_t)(q0 + l31) * E + kf*16 + 8*hi);

  f32x16 o0 = {}, o1 = {};
  float ml = 0.f, ll_par = 0.f;   // ml starts 0 (C-init = -ml); l per-lane

  const int t256 = tid & 255;
  const int srow = t256 >> 2, sc0 = (t256 & 3) * 16;
  const unsigned short* kS = kb + (size_t)(tbase + srow) * E + sc0;  // + it*64*E
  const unsigned short* vS = vb + (size_t)srow * S + tbase + sc0;    // + it*64

  uint4 kr0 = *(const uint4*)kS, kr1 = *(const uint4*)(kS + 8);
  uint4 vr0 = *(const uint4*)vS, vr1 = *(const uint4*)(vS + 8);

  constexpr int NIT = S / 2 / 64;   // 32 iterations per half
  for (int it = 0; it < NIT; ++it) {
    unsigned short (*K_lds)[72] = SM[it & 1][2*half];
    unsigned short (*V_lds)[72] = SM[it & 1][2*half + 1];

    // ---- stage tile 'it' into buf[it&1], ONE barrier ----
    *(uint4*)&K_lds[srow][sc0]     = kr0;
    *(uint4*)&K_lds[srow][sc0 + 8] = kr1;
    *(uint4*)&V_lds[srow][sc0]     = vr0;
    *(uint4*)&V_lds[srow][sc0 + 8] = vr1;
    __syncthreads();

    if (it + 1 < NIT) {  // register prefetch of next tile (T14)
      const unsigned short* kp = kS + (size_t)(it + 1) * 64 * E;
      const unsigned short* vp = vS + (it + 1) * 64;
      kr0 = *(const uint4*)kp; kr1 = *(const uint4*)(kp + 8);
      vr0 = *(const uint4*)vp; vr1 = *(const uint4*)(vp + 8);
    }

    // ---- QK^T with C-init = -ml (scores arrive pre-shifted) ----
    const float negml = 0.f - ml;   // transient, dies before MFMA chain
    f32x16 s0, s1;
    #pragma unroll
    for (int r = 0; r < 16; ++r) { s0[r] = negml; s1[r] = negml; }
    __builtin_amdgcn_s_setprio(1);
    #pragma unroll
    for (int kf = 0; kf < 4; ++kf) {
      bf16x8 ka = *(const bf16x8*)&K_lds[l31]     [kf*16 + 8*hi];
      bf16x8 kc = *(const bf16x8*)&K_lds[32 + l31][kf*16 + 8*hi];
      s0 = mfma32(ka, qf[kf], s0);
      s1 = mfma32(kc, qf[kf], s1);
    }
    __builtin_amdgcn_s_setprio(0);

    // ---- shifted lane-local max (fmax triples -> v_max3) ----
    float m0 = fmaxf(fmaxf(s0[0],  s0[1]),  s0[2]);
    float m1 = fmaxf(fmaxf(s0[3],  s0[4]),  s0[5]);
    float m2 = fmaxf(fmaxf(s0[6],  s0[7]),  s0[8]);
    float m3 = fmaxf(fmaxf(s0[9],  s0[10]), s0[11]);
    float m4 = fmaxf(fmaxf(s0[12], s0[13]), s0[14]);
    float m5 = fmaxf(fmaxf(s0[15], s1[0]),  s1[1]);
    float m6 = fmaxf(fmaxf(s1[2],  s1[3]),  s1[4]);
    float m7 = fmaxf(fmaxf(s1[5],  s1[6]),  s1[7]);
    float m8 = fmaxf(fmaxf(s1[8],  s1[9]),  s1[10]);
    float m9 = fmaxf(fmaxf(s1[11], s1[12]), s1[13]);
    float ma = fmaxf(s1[14], s1[15]);
    float tb0 = fmaxf(fmaxf(m0, m1), m2);
    float tb1 = fmaxf(fmaxf(m3, m4), m5);
    float tb2 = fmaxf(fmaxf(m6, m7), m8);
    float tm = fmaxf(fmaxf(tb0, tb1), fmaxf(tb2, fmaxf(m9, ma)));
    // no cross-half shuffle here — __all checks all 64 lanes (exact)

    if (!__all(tm <= 8.f)) {   // rare exact-rescale path (R13/R14-verified)
      tm = fmaxf(tm, __shfl_xor(tm, 32));   // pair-max so delta is q-consistent
      const float delta = fmaxf(tm, 0.f);
      const float fr = ex2(-delta);
      ml += delta; ll_par *= fr;
      #pragma unroll
      for (int r = 0; r < 16; ++r) {
        o0[r] *= fr; o1[r] *= fr;
        s0[r] -= delta; s1[r] -= delta;
      }
    }

    // ---- P = exp2(pre-shifted score); two partial-sum chains ----
    float rs0 = 0.f, rs1 = 0.f;
    #pragma unroll
    for (int r = 0; r < 16; ++r) { s0[r] = ex2(s0[r]); rs0 += s0[r]; }
    #pragma unroll
    for (int r = 0; r < 16; ++r) { s1[r] = ex2(s1[r]); rs1 += s1[r]; }
    ll_par += rs0 + rs1;

    // ---- P -> B-frags in-register: cvt_pk + permlane32_swap (T12) ----
    unsigned int a0 = cvt_pk_bf16(s0[0],  s0[1]),  a1 = cvt_pk_bf16(s0[2],  s0[3]);
    unsigned int a2 = cvt_pk_bf16(s0[4],  s0[5]),  a3 = cvt_pk_bf16(s0[6],  s0[7]);
    unsigned int a4 = cvt_pk_bf16(s0[8],  s0[9]),  a5 = cvt_pk_bf16(s0[10], s0[11]);
    unsigned int a6 = cvt_pk_bf16(s0[12], s0[13]), a7 = cvt_pk_bf16(s0[14], s0[15]);
    plswap(a0, a2); plswap(a1, a3); plswap(a4, a6); plswap(a5, a7);
    unsigned int c0 = cvt_pk_bf16(s1[0],  s1[1]),  c1 = cvt_pk_bf16(s1[2],  s1[3]);
    unsigned int c2 = cvt_pk_bf16(s1[4],  s1[5]),  c3 = cvt_pk_bf16(s1[6],  s1[7]);
    unsigned int c4 = cvt_pk_bf16(s1[8],  s1[9]),  c5 = cvt_pk_bf16(s1[10], s1[11]);
    unsigned int c6 = cvt_pk_bf16(s1[12], s1[13]), c7 = cvt_pk_bf16(s1[14], s1[15]);
    plswap(c0, c2); plswap(c1, c3); plswap(c4, c6); plswap(c5, c7);
    uint4 pa[4];
    pa[0] = uint4{a0, a1, a2, a3};  // t  0..15
    pa[1] = uint4{a4, a5, a6, a7};  // t 16..31
    pa[2] = uint4{c0, c1, c2, c3};  // t 32..47
    pa[3] = uint4{c4, c5, c6, c7};  // t 48..63

    // ---- O += V^T x P : mfma32(V_frag{rows d}, P_frag{rows q}) ----
    __builtin_amdgcn_s_setprio(1);
    #pragma unroll
    for (int tf = 0; tf < 4; ++tf) {
      bf16x8 va = *(const bf16x8*)&V_lds[l31]     [tf*16 + 8*hi];
      bf16x8 vc = *(const bf16x8*)&V_lds[32 + l31][tf*16 + 8*hi];
      bf16x8 pf = asbf(pa[tf]);
      o0 = mfma32(va, pf, o0);
      o1 = mfma32(vc, pf, o1);
    }
    __builtin_amdgcn_s_setprio(0);
    // no end-of-iteration barrier (double-buffered)
  }

  // ---- combine per-lane l across the lane^32 pair (deferred from loop) ----
  float ll = ll_par + __shfl_xor(ll_par, 32);

  // all waves must finish their last compute before staging LDS is reused
  __syncthreads();

  // ---- flash-combine across the two KV-halves via LDS ----
  // per (w4, lane): 34 floats {o0[16], o1[16], ml, ll}. stride 34 -> 2-way.
  float* cb = (float*)SM;
  float* p = cb + (size_t)(w4 * 64 + lane) * 34;
  if (half) {
    #pragma unroll
    for (int r = 0; r < 16; ++r) { p[r] = o0[r]; p[16 + r] = o1[r]; }
    p[32] = ml; p[33] = ll;
  }
  __syncthreads();
  if (!half) {
    const float m2 = p[32], l2 = p[33];
    const float m = fmaxf(ml, m2);
    const float f1 = ex2(ml - m), f2 = ex2(m2 - m);
    ll = ll * f1 + l2 * f2;
    #pragma unroll
    for (int r = 0; r < 16; ++r) {
      o0[r] = o0[r] * f1 + p[r] * f2;
      o1[r] = o1[r] * f1 + p[16 + r] * f2;
    }

    // ---- epilogue: d = (r&3)+8*(r>>2)+4*hi (+32 for o1), col q = l31 ----
    const float inv = 1.0f / ll;
    const size_t rowb = (size_t)(b * S + q0 + l31) * E + h * HD;
    #pragma unroll
    for (int qd = 0; qd < 4; ++qd) {
      uint2 w0, w1;
      w0.x = cvt_pk_bf16(o0[4*qd]     * inv, o0[4*qd + 1] * inv);
      w0.y = cvt_pk_bf16(o0[4*qd + 2] * inv, o0[4*qd + 3] * inv);
      *(uint2*)&cc[rowb + 8*qd + 4*hi] = w0;
      w1.x = cvt_pk_bf16(o1[4*qd]     * inv, o1[4*qd + 1] * inv);
      w1.y = cvt_pk_bf16(o1[4*qd + 2] * inv, o1[4*qd + 3] * inv);
      *(uint2*)&cc[rowb + 32 + 8*qd + 4*hi] = w1;
    }
  }
}

// ---------------------------------------------------------------------------
extern "C" void kernel_launch(void* const* d_in, const int* in_sizes, int n_in,
                              void* d_out, int out_size, void* d_ws, size_t ws_size,
                              hipStream_t stream) {
  const float* q  = (const float*)d_in[0];
  const float* k  = (const float*)d_in[1];
  const float* v  = (const float*)d_in[2];
  const float* Wq = (const float*)d_in[3];
  const float* bq = (const float*)d_in[4];
  const float* Wk = (const float*)d_in[5];
  const float* bk = (const float*)d_in[6];
  const float* Wv = (const float*)d_in[7];
  const float* bv = (const float*)d_in[8];
  const float* Wo = (const float*)d_in[9];
  const float* bo = (const float*)d_in[10];
  float* out = (float*)d_out;

  unsigned short* qh  = (unsigned short*)d_ws;
  unsigned short* kh  = qh + (size_t)RT * E;
  unsigned short* vhT = kh + (size_t)RT * E;
  unsigned short* cc  = vhT + (size_t)RT * E;

  // 1/sqrt(512) * log2(e): softmax runs in base-2 domain
  const float qscale = 1.4426950408889634f / 22.62741699796952f;

  gemm_qkv<<<dim3(256, 3), dim3(512), 0, stream>>>(q, k, v, Wq, bq, Wk, bk, Wv, bv,
                                                   qh, kh, vhT, qscale);
  attn_fwd<<<dim3(512), dim3(512), 0, stream>>>(qh, kh, vhT, cc);
  gemm_o<<<dim3(256), dim3(512), 0, stream>>>(cc, Wo, bo, out);
}

// Round 16
// 127.682 us; speedup vs baseline: 1.1296x; 1.0639x over previous
//
#include <hip/hip_runtime.h>
#include <hip/hip_bf16.h>

#define DEVFN __device__ __forceinline__

typedef __attribute__((ext_vector_type(8))) __bf16 bf16x8;
typedef __attribute__((ext_vector_type(4))) float f32x4;
typedef __attribute__((ext_vector_type(16))) float f32x16;

constexpr int E  = 512;   // embed
constexpr int S  = 4096;  // seq len
constexpr int HD = 64;    // head dim
constexpr int RT = 8192;  // B * S rows

DEVFN unsigned int cvt_pk_bf16(float lo, float hi) {
  unsigned int r;
  asm("v_cvt_pk_bf16_f32 %0, %1, %2" : "=v"(r) : "v"(lo), "v"(hi));
  return r;
}
DEVFN void plswap(unsigned int& a, unsigned int& b) {
  asm("v_permlane32_swap_b32 %0, %1" : "+v"(a), "+v"(b));
}
DEVFN float ex2(float x) { return __builtin_amdgcn_exp2f(x); }

DEVFN unsigned short f2bf(float f) {
  union { float f; unsigned int u; } v; v.f = f;
  unsigned int u = v.u;
  return (unsigned short)((u + 0x7fffu + ((u >> 16) & 1u)) >> 16);
}

DEVFN f32x4 mfma16(bf16x8 a, bf16x8 b, f32x4 c) {
  return __builtin_amdgcn_mfma_f32_16x16x32_bf16(a, b, c, 0, 0, 0);
}
DEVFN f32x16 mfma32(bf16x8 a, bf16x8 b, f32x16 c) {
  return __builtin_amdgcn_mfma_f32_32x32x16_bf16(a, b, c, 0, 0, 0);
}

DEVFN uint4 pk8(const float4& a, const float4& b) {
  uint4 r;
  r.x = cvt_pk_bf16(a.x, a.y); r.y = cvt_pk_bf16(a.z, a.w);
  r.z = cvt_pk_bf16(b.x, b.y); r.w = cvt_pk_bf16(b.z, b.w);
  return r;
}
DEVFN bf16x8 asbf(uint4 u) { union { uint4 a; bf16x8 b; } c; c.a = u; return c.b; }

// ---------------------------------------------------------------------------
// GEMM (NT): out[r,n] = (sum_k X[r,k]*W[n,k] + bias[n]) * scale
// Tile 128x128, BK=32, 512 threads = 8 waves (2x4 of 64x32-out waves).
// R16: double-buffered LDS, ONE barrier per K-step (R15-verified recipe):
// write staged regs into buf[p] -> barrier -> prefetch next + compute
// from buf[p]. Race-free: each barrier segment touches one buffer; R(p)
// completes for all waves before any wave can write p again. BK=32 keeps
// the double buffer at 41 KB -> 3 blocks/CU preserved for gemm_qkv.
// XCD-chunked block swizzle (T1, bijective bit-permutation).
// OMODE: 0 = bf16 row-major, 1 = f32 row-major, 2 = bf16 transposed per batch
// ---------------------------------------------------------------------------
template<typename TIN, int OMODE>
DEVFN void gemm_body(const TIN* __restrict__ X, const float* __restrict__ W,
                     const float* __restrict__ bias, void* __restrict__ outp,
                     float scale,
                     unsigned short (*Al)[128][40], unsigned short (*Bl)[128][40]) {
  const int bid0 = blockIdx.x;
  const int bid = ((bid0 & 7) << 5) | (bid0 >> 3);   // bijective, 256 blocks
  const int bm = bid >> 2, bn = bid & 3;   // 64 x 4 blocks
  const int tid = threadIdx.x;
  const int w = tid >> 6, lane = tid & 63;
  const int g = lane >> 4, ln = lane & 15;
  const int wm = w >> 2, wn = w & 3;       // 2 x 4 waves
  const int r0 = bm * 128, n0 = bn * 128;
  const int srw = tid >> 2, sc0 = (tid & 3) * 8;  // staging: 4 thr/row, 8 elems

  f32x4 acc[4][2] = {};

  float4 af0, af1;   // fp32 A prefetch (8 floats)
  uint4  au;         // bf16 A prefetch (8 elems)
  float4 bp0, bp1;   // fp32 B prefetch

  auto loadA = [&](int k0) {
    if constexpr (sizeof(TIN) == 4) {
      const float* src = (const float*)X + (size_t)(r0 + srw) * E + k0 + sc0;
      af0 = *(const float4*)src;
      af1 = *(const float4*)(src + 4);
    } else {
      const unsigned short* src = (const unsigned short*)X + (size_t)(r0 + srw) * E + k0 + sc0;
      au = *(const uint4*)src;
    }
  };
  auto loadB = [&](int k0) {
    const float* src = W + (size_t)(n0 + srw) * E + k0 + sc0;
    bp0 = *(const float4*)src;
    bp1 = *(const float4*)(src + 4);
  };

  loadA(0); loadB(0);

  #pragma unroll 4
  for (int it = 0; it < E / 32; ++it) {
    const int p = it & 1;
    // ---- stage tile 'it' into buf[p], ONE barrier ----
    if constexpr (sizeof(TIN) == 4)
      *(uint4*)&Al[p][srw][sc0] = pk8(af0, af1);
    else
      *(uint4*)&Al[p][srw][sc0] = au;
    *(uint4*)&Bl[p][srw][sc0] = pk8(bp0, bp1);
    __syncthreads();

    if (it + 1 < E / 32) { loadA((it + 1) * 32); loadB((it + 1) * 32); }

    __builtin_amdgcn_s_setprio(1);
    bf16x8 afr[4], bfr[2];
    #pragma unroll
    for (int i = 0; i < 4; ++i)
      afr[i] = *(const bf16x8*)&Al[p][wm*64 + i*16 + ln][8*g];
    #pragma unroll
    for (int j = 0; j < 2; ++j)
      bfr[j] = *(const bf16x8*)&Bl[p][wn*32 + j*16 + ln][8*g];
    #pragma unroll
    for (int i = 0; i < 4; ++i)
      #pragma unroll
      for (int j = 0; j < 2; ++j)
        acc[i][j] = mfma16(afr[i], bfr[j], acc[i][j]);
    __builtin_amdgcn_s_setprio(0);
    // no trailing barrier (double-buffered)
  }

  // epilogue: C/D layout col=lane&15, row=4*(lane>>4)+reg
  #pragma unroll
  for (int j = 0; j < 2; ++j) {
    const int gcol = n0 + wn*32 + j*16 + ln;
    const float bv = bias[gcol];
    #pragma unroll
    for (int i = 0; i < 4; ++i) {
      const int gr = r0 + wm*64 + i*16 + 4*g;
      #pragma unroll
      for (int r = 0; r < 4; ++r) {
        const float v = (acc[i][j][r] + bv) * scale;
        if constexpr (OMODE == 1)
          ((float*)outp)[(size_t)(gr + r) * E + gcol] = v;
        else if constexpr (OMODE == 0)
          ((unsigned short*)outp)[(size_t)(gr + r) * E + gcol] = f2bf(v);
        else
          ((unsigned short*)outp)[((size_t)((gr + r) >> 12) * E + gcol) * S + ((gr + r) & (S - 1))] = f2bf(v);
      }
    }
  }
}

__global__ __launch_bounds__(512) void gemm_qkv(const float* __restrict__ q,
    const float* __restrict__ k, const float* __restrict__ v,
    const float* __restrict__ Wq, const float* __restrict__ bq,
    const float* __restrict__ Wk, const float* __restrict__ bk,
    const float* __restrict__ Wv, const float* __restrict__ bv,
    unsigned short* qh, unsigned short* kh, unsigned short* vhT, float qscale) {
  __shared__ unsigned short Al[2][128][40];
  __shared__ unsigned short Bl[2][128][40];
  const int y = blockIdx.y;
  if (y == 0)      gemm_body<float, 0>(q, Wq, bq, qh, qscale, Al, Bl);
  else if (y == 1) gemm_body<float, 0>(k, Wk, bk, kh, 1.0f, Al, Bl);
  else             gemm_body<float, 2>(v, Wv, bv, vhT, 1.0f, Al, Bl);
}

__global__ __launch_bounds__(512) void gemm_o(const unsigned short* __restrict__ cc,
    const float* __restrict__ Wo, const float* __restrict__ bo, float* out) {
  __shared__ unsigned short Al[2][128][40];
  __shared__ unsigned short Bl[2][128][40];
  gemm_body<unsigned short, 1>(cc, Wo, bo, out, 1.0f, Al, Bl);
}

// ---------------------------------------------------------------------------
// Flash attention, 32x32 MFMA, in-block KV-split (R15-VERIFIED, 88.0 us):
// double-buffered KV staging, one barrier/iter; C-init=-ml pre-shifted
// scores; lane-local max, shfl only in rare branch; per-lane l deferred.
// UNCHANGED from R15.
// ---------------------------------------------------------------------------
__global__ __launch_bounds__(512, 4) void attn_fwd(const unsigned short* __restrict__ qh,
                                                   const unsigned short* __restrict__ kh,
                                                   const unsigned short* __restrict__ vhT,
                                                   unsigned short* __restrict__ cc) {
  // [buf][2*half+0]=K [t][d], [buf][2*half+1]=V [d][t]; 73,728 B total
  __shared__ unsigned short SM[2][4][64][72];

  const int bid = blockIdx.x;
  const int swz = (bid & 7) * 64 + (bid >> 3);   // XCD-bijective: 2 heads/XCD-L2
  const int bh = swz >> 5, qt = swz & 31;
  const int b = bh >> 3, h = bh & 7;

  const int tid = threadIdx.x;
  const int wv = tid >> 6, lane = tid & 63;
  const int half = wv >> 2, w4 = wv & 3;
  const int l31 = lane & 31, hi = lane >> 5;

  const unsigned short* qb = qh + (size_t)b * S * E + h * HD;
  const unsigned short* kb = kh + (size_t)b * S * E + h * HD;
  const unsigned short* vb = vhT + ((size_t)b * E + h * HD) * S;
  const int q0 = qt * 128 + w4 * 32;
  const int tbase = half * (S / 2);

  // Q as B-operand: q = q0+l31, d = kf*16 + 8*hi + j
  bf16x8 qf[4];
  #pragma unroll
  for (int kf = 0; kf < 4; ++kf)
    qf[kf] = *(const bf16x8*)(qb + (size_t)(q0 + l31) * E + kf*16 + 8*hi);

  f32x16 o0 = {}, o1 = {};
  float ml = 0.f, ll_par = 0.f;   // ml starts 0 (C-init = -ml); l per-lane

  const int t256 = tid & 255;
  const int srow = t256 >> 2, sc0 = (t256 & 3) * 16;
  const unsigned short* kS = kb + (size_t)(tbase + srow) * E + sc0;  // + it*64*E
  const unsigned short* vS = vb + (size_t)srow * S + tbase + sc0;    // + it*64

  uint4 kr0 = *(const uint4*)kS, kr1 = *(const uint4*)(kS + 8);
  uint4 vr0 = *(const uint4*)vS, vr1 = *(const uint4*)(vS + 8);

  constexpr int NIT = S / 2 / 64;   // 32 iterations per half
  for (int it = 0; it < NIT; ++it) {
    unsigned short (*K_lds)[72] = SM[it & 1][2*half];
    unsigned short (*V_lds)[72] = SM[it & 1][2*half + 1];

    // ---- stage tile 'it' into buf[it&1], ONE barrier ----
    *(uint4*)&K_lds[srow][sc0]     = kr0;
    *(uint4*)&K_lds[srow][sc0 + 8] = kr1;
    *(uint4*)&V_lds[srow][sc0]     = vr0;
    *(uint4*)&V_lds[srow][sc0 + 8] = vr1;
    __syncthreads();

    if (it + 1 < NIT) {  // register prefetch of next tile (T14)
      const unsigned short* kp = kS + (size_t)(it + 1) * 64 * E;
      const unsigned short* vp = vS + (it + 1) * 64;
      kr0 = *(const uint4*)kp; kr1 = *(const uint4*)(kp + 8);
      vr0 = *(const uint4*)vp; vr1 = *(const uint4*)(vp + 8);
    }

    // ---- QK^T with C-init = -ml (scores arrive pre-shifted) ----
    const float negml = 0.f - ml;   // transient, dies before MFMA chain
    f32x16 s0, s1;
    #pragma unroll
    for (int r = 0; r < 16; ++r) { s0[r] = negml; s1[r] = negml; }
    __builtin_amdgcn_s_setprio(1);
    #pragma unroll
    for (int kf = 0; kf < 4; ++kf) {
      bf16x8 ka = *(const bf16x8*)&K_lds[l31]     [kf*16 + 8*hi];
      bf16x8 kc = *(const bf16x8*)&K_lds[32 + l31][kf*16 + 8*hi];
      s0 = mfma32(ka, qf[kf], s0);
      s1 = mfma32(kc, qf[kf], s1);
    }
    __builtin_amdgcn_s_setprio(0);

    // ---- shifted lane-local max (fmax triples -> v_max3) ----
    float m0 = fmaxf(fmaxf(s0[0],  s0[1]),  s0[2]);
    float m1 = fmaxf(fmaxf(s0[3],  s0[4]),  s0[5]);
    float m2 = fmaxf(fmaxf(s0[6],  s0[7]),  s0[8]);
    float m3 = fmaxf(fmaxf(s0[9],  s0[10]), s0[11]);
    float m4 = fmaxf(fmaxf(s0[12], s0[13]), s0[14]);
    float m5 = fmaxf(fmaxf(s0[15], s1[0]),  s1[1]);
    float m6 = fmaxf(fmaxf(s1[2],  s1[3]),  s1[4]);
    float m7 = fmaxf(fmaxf(s1[5],  s1[6]),  s1[7]);
    float m8 = fmaxf(fmaxf(s1[8],  s1[9]),  s1[10]);
    float m9 = fmaxf(fmaxf(s1[11], s1[12]), s1[13]);
    float ma = fmaxf(s1[14], s1[15]);
    float tb0 = fmaxf(fmaxf(m0, m1), m2);
    float tb1 = fmaxf(fmaxf(m3, m4), m5);
    float tb2 = fmaxf(fmaxf(m6, m7), m8);
    float tm = fmaxf(fmaxf(tb0, tb1), fmaxf(tb2, fmaxf(m9, ma)));
    // no cross-half shuffle here — __all checks all 64 lanes (exact)

    if (!__all(tm <= 8.f)) {   // rare exact-rescale path (R13/R14-verified)
      tm = fmaxf(tm, __shfl_xor(tm, 32));   // pair-max so delta is q-consistent
      const float delta = fmaxf(tm, 0.f);
      const float fr = ex2(-delta);
      ml += delta; ll_par *= fr;
      #pragma unroll
      for (int r = 0; r < 16; ++r) {
        o0[r] *= fr; o1[r] *= fr;
        s0[r] -= delta; s1[r] -= delta;
      }
    }

    // ---- P = exp2(pre-shifted score); two partial-sum chains ----
    float rs0 = 0.f, rs1 = 0.f;
    #pragma unroll
    for (int r = 0; r < 16; ++r) { s0[r] = ex2(s0[r]); rs0 += s0[r]; }
    #pragma unroll
    for (int r = 0; r < 16; ++r) { s1[r] = ex2(s1[r]); rs1 += s1[r]; }
    ll_par += rs0 + rs1;

    // ---- P -> B-frags in-register: cvt_pk + permlane32_swap (T12) ----
    unsigned int a0 = cvt_pk_bf16(s0[0],  s0[1]),  a1 = cvt_pk_bf16(s0[2],  s0[3]);
    unsigned int a2 = cvt_pk_bf16(s0[4],  s0[5]),  a3 = cvt_pk_bf16(s0[6],  s0[7]);
    unsigned int a4 = cvt_pk_bf16(s0[8],  s0[9]),  a5 = cvt_pk_bf16(s0[10], s0[11]);
    unsigned int a6 = cvt_pk_bf16(s0[12], s0[13]), a7 = cvt_pk_bf16(s0[14], s0[15]);
    plswap(a0, a2); plswap(a1, a3); plswap(a4, a6); plswap(a5, a7);
    unsigned int c0 = cvt_pk_bf16(s1[0],  s1[1]),  c1 = cvt_pk_bf16(s1[2],  s1[3]);
    unsigned int c2 = cvt_pk_bf16(s1[4],  s1[5]),  c3 = cvt_pk_bf16(s1[6],  s1[7]);
    unsigned int c4 = cvt_pk_bf16(s1[8],  s1[9]),  c5 = cvt_pk_bf16(s1[10], s1[11]);
    unsigned int c6 = cvt_pk_bf16(s1[12], s1[13]), c7 = cvt_pk_bf16(s1[14], s1[15]);
    plswap(c0, c2); plswap(c1, c3); plswap(c4, c6); plswap(c5, c7);
    uint4 pa[4];
    pa[0] = uint4{a0, a1, a2, a3};  // t  0..15
    pa[1] = uint4{a4, a5, a6, a7};  // t 16..31
    pa[2] = uint4{c0, c1, c2, c3};  // t 32..47
    pa[3] = uint4{c4, c5, c6, c7};  // t 48..63

    // ---- O += V^T x P : mfma32(V_frag{rows d}, P_frag{rows q}) ----
    __builtin_amdgcn_s_setprio(1);
    #pragma unroll
    for (int tf = 0; tf < 4; ++tf) {
      bf16x8 va = *(const bf16x8*)&V_lds[l31]     [tf*16 + 8*hi];
      bf16x8 vc = *(const bf16x8*)&V_lds[32 + l31][tf*16 + 8*hi];
      bf16x8 pf = asbf(pa[tf]);
      o0 = mfma32(va, pf, o0);
      o1 = mfma32(vc, pf, o1);
    }
    __builtin_amdgcn_s_setprio(0);
    // no end-of-iteration barrier (double-buffered)
  }

  // ---- combine per-lane l across the lane^32 pair (deferred from loop) ----
  float ll = ll_par + __shfl_xor(ll_par, 32);

  // all waves must finish their last compute before staging LDS is reused
  __syncthreads();

  // ---- flash-combine across the two KV-halves via LDS ----
  // per (w4, lane): 34 floats {o0[16], o1[16], ml, ll}. stride 34 -> 2-way.
  float* cb = (float*)SM;
  float* p = cb + (size_t)(w4 * 64 + lane) * 34;
  if (half) {
    #pragma unroll
    for (int r = 0; r < 16; ++r) { p[r] = o0[r]; p[16 + r] = o1[r]; }
    p[32] = ml; p[33] = ll;
  }
  __syncthreads();
  if (!half) {
    const float m2 = p[32], l2 = p[33];
    const float m = fmaxf(ml, m2);
    const float f1 = ex2(ml - m), f2 = ex2(m2 - m);
    ll = ll * f1 + l2 * f2;
    #pragma unroll
    for (int r = 0; r < 16; ++r) {
      o0[r] = o0[r] * f1 + p[r] * f2;
      o1[r] = o1[r] * f1 + p[16 + r] * f2;
    }

    // ---- epilogue: d = (r&3)+8*(r>>2)+4*hi (+32 for o1), col q = l31 ----
    const float inv = 1.0f / ll;
    const size_t rowb = (size_t)(b * S + q0 + l31) * E + h * HD;
    #pragma unroll
    for (int qd = 0; qd < 4; ++qd) {
      uint2 w0, w1;
      w0.x = cvt_pk_bf16(o0[4*qd]     * inv, o0[4*qd + 1] * inv);
      w0.y = cvt_pk_bf16(o0[4*qd + 2] * inv, o0[4*qd + 3] * inv);
      *(uint2*)&cc[rowb + 8*qd + 4*hi] = w0;
      w1.x = cvt_pk_bf16(o1[4*qd]     * inv, o1[4*qd + 1] * inv);
      w1.y = cvt_pk_bf16(o1[4*qd + 2] * inv, o1[4*qd + 3] * inv);
      *(uint2*)&cc[rowb + 32 + 8*qd + 4*hi] = w1;
    }
  }
}

// ---------------------------------------------------------------------------
extern "C" void kernel_launch(void* const* d_in, const int* in_sizes, int n_in,
                              void* d_out, int out_size, void* d_ws, size_t ws_size,
                              hipStream_t stream) {
  const float* q  = (const float*)d_in[0];
  const float* k  = (const float*)d_in[1];
  const float* v  = (const float*)d_in[2];
  const float* Wq = (const float*)d_in[3];
  const float* bq = (const float*)d_in[4];
  const float* Wk = (const float*)d_in[5];
  const float* bk = (const float*)d_in[6];
  const float* Wv = (const float*)d_in[7];
  const float* bv = (const float*)d_in[8];
  const float* Wo = (const float*)d_in[9];
  const float* bo = (const float*)d_in[10];
  float* out = (float*)d_out;

  unsigned short* qh  = (unsigned short*)d_ws;
  unsigned short* kh  = qh + (size_t)RT * E;
  unsigned short* vhT = kh + (size_t)RT * E;
  unsigned short* cc  = vhT + (size_t)RT * E;

  // 1/sqrt(512) * log2(e): softmax runs in base-2 domain
  const float qscale = 1.4426950408889634f / 22.62741699796952f;

  gemm_qkv<<<dim3(256, 3), dim3(512), 0, stream>>>(q, k, v, Wq, bq, Wk, bk, Wv, bv,
                                                   qh, kh, vhT, qscale);
  attn_fwd<<<dim3(512), dim3(512), 0, stream>>>(qh, kh, vhT, cc);
  gemm_o<<<dim3(256), dim3(512), 0, stream>>>(cc, Wo, bo, out);
}